// Round 7
// baseline (458.752 us; speedup 1.0000x reference)
//
#include <hip/hip_runtime.h>
#include <stdint.h>

#define NBINS 256
#define NCOPY 32        // one sub-histogram per LDS bank -> 32 KiB LDS
#define GRID_BLKS 1024  // 4 blocks/CU: 128 KiB LDS of 160 -> co-residency w/ slack
#define TPB 256
#define BAR0 320        // ws word offsets for barrier counters

// Monotonic float<->uint mapping so atomicMin/Max on uint32 order like floats.
__device__ __forceinline__ uint32_t f2mono(float f) {
    uint32_t u = __float_as_uint(f);
    return (u & 0x80000000u) ? ~u : (u | 0x80000000u);
}
__device__ __forceinline__ float mono2f(uint32_t u) {
    uint32_t b = (u & 0x80000000u) ? (u & 0x7FFFFFFFu) : ~u;
    return __uint_as_float(b);
}

// Exact replication of jnp.histogram edge: edges[i] = f32(f32(i*delta) + min)
__device__ __forceinline__ float edge_at(int i, float minv, float delta) {
    return __fadd_rn(__fmul_rn((float)i, delta), minv);
}

__device__ __forceinline__ float min4(float4 v) {
    return fminf(fminf(v.x, v.y), fminf(v.z, v.w));
}
__device__ __forceinline__ float max4(float4 v) {
    return fmaxf(fmaxf(v.x, v.y), fmaxf(v.z, v.w));
}

// bin = clamp((v-min)*256/(max-min), 0, 255). ±1ulp edge misbinning shifts a
// handful of counts out of 33.5M -> var12 argmax unaffected; threshold value
// itself stays bit-exact (computed from min/max only).
__device__ __forceinline__ int bin_of(float v, float minv, float invd) {
    float t = (v - minv) * invd;
    t = fminf(fmaxf(t, 0.0f), 255.0f);
    return (int)t;
}

__device__ __forceinline__ uint32_t aload(const uint32_t* p) {
    return __hip_atomic_load(p, __ATOMIC_RELAXED, __HIP_MEMORY_SCOPE_AGENT);
}

// Device-scope software grid barrier. Counter pre-zeroed by k_init each call.
// Fail-safe spin cap: if co-residency ever breaks, we produce a wrong answer
// fast (bench fails with absmax) instead of a 600s timeout.
__device__ __forceinline__ void grid_barrier(uint32_t* bar, uint32_t expect) {
    __syncthreads();
    if (threadIdx.x == 0) {
        __threadfence();
        __hip_atomic_fetch_add(bar, 1u, __ATOMIC_RELEASE, __HIP_MEMORY_SCOPE_AGENT);
        uint32_t spins = 0;
        while (__hip_atomic_load(bar, __ATOMIC_ACQUIRE, __HIP_MEMORY_SCOPE_AGENT) < expect) {
            __builtin_amdgcn_s_sleep(8);
            if (++spins > 100000000u) break;
        }
    }
    __syncthreads();
}

// ws layout (uint32 words):
// [0] min_mono [1] max_mono [2] thresh bits [4..4+NBINS) hist [320..324) barriers
__global__ void k_init(uint32_t* ws) {
    int i = threadIdx.x;
    if (i == 0) ws[0] = 0xFFFFFFFFu;
    if (i == 1) ws[1] = 0u;
    if (i == 2) ws[2] = 0u;
    if (i >= 4 && i < 4 + NBINS) ws[i] = 0u;
    if (i >= BAR0 && i < BAR0 + 4) ws[i] = 0u;
}

__global__ void __launch_bounds__(TPB, 4) k_fused(const float* __restrict__ in,
                                                  float* __restrict__ out,
                                                  int n, uint32_t* ws) {
    __shared__ uint32_t h[NBINS * NCOPY];  // 32 KiB, reused per phase
    float* sf = (float*)h;

    const int gtid = blockIdx.x * blockDim.x + threadIdx.x;
    const int gstride = gridDim.x * blockDim.x;
    const int wave = threadIdx.x >> 6, lane = threadIdx.x & 63;
    const int n4 = n >> 2;
    const float4* in4 = (const float4*)in;
    const uint32_t expect = gridDim.x;

    // ===== Phase A: global min/max (MLP=8) =====
    {
        float vmin = INFINITY, vmax = -INFINITY;
        int i = gtid;
        for (; i + 7 * gstride < n4; i += 8 * gstride) {
            float4 v0 = in4[i];
            float4 v1 = in4[i + gstride];
            float4 v2 = in4[i + 2 * gstride];
            float4 v3 = in4[i + 3 * gstride];
            float4 v4 = in4[i + 4 * gstride];
            float4 v5 = in4[i + 5 * gstride];
            float4 v6 = in4[i + 6 * gstride];
            float4 v7 = in4[i + 7 * gstride];
            float mn0 = fminf(fminf(min4(v0), min4(v1)), fminf(min4(v2), min4(v3)));
            float mn1 = fminf(fminf(min4(v4), min4(v5)), fminf(min4(v6), min4(v7)));
            float mx0 = fmaxf(fmaxf(max4(v0), max4(v1)), fmaxf(max4(v2), max4(v3)));
            float mx1 = fmaxf(fmaxf(max4(v4), max4(v5)), fmaxf(max4(v6), max4(v7)));
            vmin = fminf(vmin, fminf(mn0, mn1));
            vmax = fmaxf(vmax, fmaxf(mx0, mx1));
        }
        for (; i < n4; i += gstride) {
            float4 v = in4[i];
            vmin = fminf(vmin, min4(v));
            vmax = fmaxf(vmax, max4(v));
        }
        for (int j = (n4 << 2) + gtid; j < n; j += gstride) {
            float v = in[j];
            vmin = fminf(vmin, v);
            vmax = fmaxf(vmax, v);
        }
#pragma unroll
        for (int off = 32; off > 0; off >>= 1) {
            vmin = fminf(vmin, __shfl_down(vmin, off));
            vmax = fmaxf(vmax, __shfl_down(vmax, off));
        }
        if (lane == 0) { sf[wave] = vmin; sf[8 + wave] = vmax; }
        __syncthreads();
        if (threadIdx.x == 0) {
            float m = sf[0], M = sf[8];
            for (int w = 1; w < 4; ++w) { m = fminf(m, sf[w]); M = fmaxf(M, sf[8 + w]); }
            atomicMin(&ws[0], f2mono(m));
            atomicMax(&ws[1], f2mono(M));
        }
    }
    grid_barrier(&ws[BAR0 + 0], expect);

    // ===== Phase B: histogram (per-bank sub-histograms, MLP=4) =====
    {
        float minv = mono2f(aload(&ws[0]));
        float maxv = mono2f(aload(&ws[1]));
        float invd = __fdiv_rn(256.0f, __fsub_rn(maxv, minv));
        int c = threadIdx.x & (NCOPY - 1);
        for (int i = threadIdx.x; i < NBINS * NCOPY; i += blockDim.x) h[i] = 0;
        __syncthreads();

        int i = gtid;
        for (; i + 3 * gstride < n4; i += 4 * gstride) {
            float4 q0 = in4[i];
            float4 q1 = in4[i + gstride];
            float4 q2 = in4[i + 2 * gstride];
            float4 q3 = in4[i + 3 * gstride];
            atomicAdd(&h[bin_of(q0.x, minv, invd) * NCOPY + c], 1u);
            atomicAdd(&h[bin_of(q0.y, minv, invd) * NCOPY + c], 1u);
            atomicAdd(&h[bin_of(q0.z, minv, invd) * NCOPY + c], 1u);
            atomicAdd(&h[bin_of(q0.w, minv, invd) * NCOPY + c], 1u);
            atomicAdd(&h[bin_of(q1.x, minv, invd) * NCOPY + c], 1u);
            atomicAdd(&h[bin_of(q1.y, minv, invd) * NCOPY + c], 1u);
            atomicAdd(&h[bin_of(q1.z, minv, invd) * NCOPY + c], 1u);
            atomicAdd(&h[bin_of(q1.w, minv, invd) * NCOPY + c], 1u);
            atomicAdd(&h[bin_of(q2.x, minv, invd) * NCOPY + c], 1u);
            atomicAdd(&h[bin_of(q2.y, minv, invd) * NCOPY + c], 1u);
            atomicAdd(&h[bin_of(q2.z, minv, invd) * NCOPY + c], 1u);
            atomicAdd(&h[bin_of(q2.w, minv, invd) * NCOPY + c], 1u);
            atomicAdd(&h[bin_of(q3.x, minv, invd) * NCOPY + c], 1u);
            atomicAdd(&h[bin_of(q3.y, minv, invd) * NCOPY + c], 1u);
            atomicAdd(&h[bin_of(q3.z, minv, invd) * NCOPY + c], 1u);
            atomicAdd(&h[bin_of(q3.w, minv, invd) * NCOPY + c], 1u);
        }
        for (; i < n4; i += gstride) {
            float4 q = in4[i];
            atomicAdd(&h[bin_of(q.x, minv, invd) * NCOPY + c], 1u);
            atomicAdd(&h[bin_of(q.y, minv, invd) * NCOPY + c], 1u);
            atomicAdd(&h[bin_of(q.z, minv, invd) * NCOPY + c], 1u);
            atomicAdd(&h[bin_of(q.w, minv, invd) * NCOPY + c], 1u);
        }
        for (int j = (n4 << 2) + gtid; j < n; j += gstride) {
            atomicAdd(&h[bin_of(in[j], minv, invd) * NCOPY + c], 1u);
        }
        __syncthreads();
        for (int b = threadIdx.x; b < NBINS; b += blockDim.x) {
            uint32_t s = 0;
#pragma unroll
            for (int k = 0; k < NCOPY; ++k) s += h[b * NCOPY + k];
            if (s) atomicAdd(&ws[4 + b], s);
        }
    }
    grid_barrier(&ws[BAR0 + 1], expect);

    // ===== Phase C: Otsu on block 0 (bit-exact f32 replication) =====
    if (blockIdx.x == 0) {
        float* cnt = sf;
        float* ctr = sf + NBINS;
        float* w1 = sf + 2 * NBINS;
        float* w2 = sf + 3 * NBINS;
        float* cs = sf + 4 * NBINS;
        float* csr = sf + 5 * NBINS;
        float* scan = sf + 6 * NBINS;
        int i = threadIdx.x;
        float minv = mono2f(aload(&ws[0]));
        float maxv = mono2f(aload(&ws[1]));
        float delta = __fdiv_rn(__fsub_rn(maxv, minv), 256.0f);

        cnt[i] = (float)aload(&ws[4 + i]);
        float e0 = edge_at(i, minv, delta);
        float e1 = edge_at(i + 1, minv, delta);
        ctr[i] = __fmul_rn(0.5f, __fadd_rn(e0, e1));
        __syncthreads();

        scan[i] = cnt[i]; __syncthreads();
        for (int off = 1; off < NBINS; off <<= 1) {
            float v = scan[i];
            if (i >= off) v = __fadd_rn(scan[i - off], v);
            __syncthreads(); scan[i] = v; __syncthreads();
        }
        w1[i] = scan[i]; __syncthreads();

        scan[i] = __fmul_rn(cnt[i], ctr[i]); __syncthreads();
        for (int off = 1; off < NBINS; off <<= 1) {
            float v = scan[i];
            if (i >= off) v = __fadd_rn(scan[i - off], v);
            __syncthreads(); scan[i] = v; __syncthreads();
        }
        cs[i] = scan[i]; __syncthreads();

        scan[i] = cnt[i]; __syncthreads();
        for (int off = 1; off < NBINS; off <<= 1) {
            float v = scan[i];
            if (i + off < NBINS) v = __fadd_rn(v, scan[i + off]);
            __syncthreads(); scan[i] = v; __syncthreads();
        }
        w2[i] = scan[i]; __syncthreads();

        scan[i] = __fmul_rn(cnt[i], ctr[i]); __syncthreads();
        for (int off = 1; off < NBINS; off <<= 1) {
            float v = scan[i];
            if (i + off < NBINS) v = __fadd_rn(v, scan[i + off]);
            __syncthreads(); scan[i] = v; __syncthreads();
        }
        csr[i] = scan[i]; __syncthreads();

        if (i < NBINS - 1) {
            float m1 = __fdiv_rn(cs[i], fmaxf(w1[i], 1.0f));
            float m2 = __fdiv_rn(csr[i + 1], fmaxf(w2[i + 1], 1.0f));
            float d = __fsub_rn(m1, m2);
            float sq = __fmul_rn(d, d);
            scan[i] = __fmul_rn(__fmul_rn(w1[i], w2[i + 1]), sq);
        }
        __syncthreads();
        if (i == 0) {
            int best = 0; float bv = scan[0];
            for (int k = 1; k < NBINS - 1; ++k) {
                float v = scan[k];
                if (v > bv) { bv = v; best = k; }  // first-max like jnp.argmax
            }
            __hip_atomic_store(&ws[2], __float_as_uint(ctr[best]),
                               __ATOMIC_RELEASE, __HIP_MEMORY_SCOPE_AGENT);
        }
    }
    grid_barrier(&ws[BAR0 + 2], expect);

    // ===== Phase D: binarize (MLP=4, plain stores) =====
    {
        float t = __uint_as_float(aload(&ws[2]));
        float4* out4 = (float4*)out;
        int i = gtid;
        for (; i + 3 * gstride < n4; i += 4 * gstride) {
            float4 v0 = in4[i];
            float4 v1 = in4[i + gstride];
            float4 v2 = in4[i + 2 * gstride];
            float4 v3 = in4[i + 3 * gstride];
            float4 r0, r1, r2, r3;
            r0.x = v0.x > t ? 1.0f : 0.0f; r0.y = v0.y > t ? 1.0f : 0.0f;
            r0.z = v0.z > t ? 1.0f : 0.0f; r0.w = v0.w > t ? 1.0f : 0.0f;
            r1.x = v1.x > t ? 1.0f : 0.0f; r1.y = v1.y > t ? 1.0f : 0.0f;
            r1.z = v1.z > t ? 1.0f : 0.0f; r1.w = v1.w > t ? 1.0f : 0.0f;
            r2.x = v2.x > t ? 1.0f : 0.0f; r2.y = v2.y > t ? 1.0f : 0.0f;
            r2.z = v2.z > t ? 1.0f : 0.0f; r2.w = v2.w > t ? 1.0f : 0.0f;
            r3.x = v3.x > t ? 1.0f : 0.0f; r3.y = v3.y > t ? 1.0f : 0.0f;
            r3.z = v3.z > t ? 1.0f : 0.0f; r3.w = v3.w > t ? 1.0f : 0.0f;
            out4[i] = r0;
            out4[i + gstride] = r1;
            out4[i + 2 * gstride] = r2;
            out4[i + 3 * gstride] = r3;
        }
        for (; i < n4; i += gstride) {
            float4 v = in4[i];
            float4 r;
            r.x = v.x > t ? 1.0f : 0.0f;
            r.y = v.y > t ? 1.0f : 0.0f;
            r.z = v.z > t ? 1.0f : 0.0f;
            r.w = v.w > t ? 1.0f : 0.0f;
            out4[i] = r;
        }
        for (int j = (n4 << 2) + gtid; j < n; j += gstride) {
            out[j] = in[j] > t ? 1.0f : 0.0f;
        }
    }
}

extern "C" void kernel_launch(void* const* d_in, const int* in_sizes, int n_in,
                              void* d_out, int out_size, void* d_ws, size_t ws_size,
                              hipStream_t stream) {
    const float* in = (const float*)d_in[0];
    float* out = (float*)d_out;
    uint32_t* ws = (uint32_t*)d_ws;
    int n = in_sizes[0];

    hipLaunchKernelGGL(k_init, dim3(1), dim3(512), 0, stream, ws);
    hipLaunchKernelGGL(k_fused, dim3(GRID_BLKS), dim3(TPB), 0, stream,
                       in, out, n, ws);
}

// Round 8
// 328.749 us; speedup vs baseline: 1.3954x; 1.3954x over previous
//
#include <hip/hip_runtime.h>
#include <stdint.h>

#define NBINS 256
#define NCOPY 32        // one sub-histogram per LDS bank -> 32 KiB LDS
#define GRID_BLKS 1024  // 4 blocks/CU: 128 KiB LDS of 160 -> co-residency w/ slack
#define TPB 256
#define BAR0 320        // ws word offset for barrier counters

// Monotonic float<->uint mapping so atomicMin/Max on uint32 order like floats.
__device__ __forceinline__ uint32_t f2mono(float f) {
    uint32_t u = __float_as_uint(f);
    return (u & 0x80000000u) ? ~u : (u | 0x80000000u);
}
__device__ __forceinline__ float mono2f(uint32_t u) {
    uint32_t b = (u & 0x80000000u) ? (u & 0x7FFFFFFFu) : ~u;
    return __uint_as_float(b);
}

// Exact replication of jnp.histogram edge: edges[i] = f32(f32(i*delta) + min)
__device__ __forceinline__ float edge_at(int i, float minv, float delta) {
    return __fadd_rn(__fmul_rn((float)i, delta), minv);
}

__device__ __forceinline__ float min4(float4 v) {
    return fminf(fminf(v.x, v.y), fminf(v.z, v.w));
}
__device__ __forceinline__ float max4(float4 v) {
    return fmaxf(fmaxf(v.x, v.y), fmaxf(v.z, v.w));
}

// bin = clamp((v-min)*256/(max-min), 0, 255). ±1ulp edge misbinning shifts a
// handful of counts out of 33.5M -> var12 argmax unaffected; threshold value
// itself stays bit-exact (computed from min/max only).
__device__ __forceinline__ int bin_of(float v, float minv, float invd) {
    float t = (v - minv) * invd;
    t = fminf(fmaxf(t, 0.0f), 255.0f);
    return (int)t;
}

__device__ __forceinline__ uint32_t aload(const uint32_t* p) {
    return __hip_atomic_load(p, __ATOMIC_RELAXED, __HIP_MEMORY_SCOPE_AGENT);
}

// Device-scope software grid barrier. RELAXED polling (no per-iteration cache
// invalidate!); exactly one release fence before the add and one acquire fence
// after the spin. Counter pre-zeroed by k_init each call. Spin cap = fail fast
// (wrong answer -> bench absmax fail) instead of a 600s hang if residency breaks.
__device__ __forceinline__ void grid_barrier(uint32_t* bar, uint32_t expect) {
    __syncthreads();
    if (threadIdx.x == 0) {
        __threadfence();  // release our global writes
        __hip_atomic_fetch_add(bar, 1u, __ATOMIC_RELAXED, __HIP_MEMORY_SCOPE_AGENT);
        uint32_t spins = 0;
        while (__hip_atomic_load(bar, __ATOMIC_RELAXED, __HIP_MEMORY_SCOPE_AGENT) < expect) {
            __builtin_amdgcn_s_sleep(2);
            if (++spins > 20000000u) break;
        }
        __threadfence();  // acquire: one invalidate, after everyone arrived
    }
    __syncthreads();
}

// ws layout (uint32 words):
// [0] min_mono [1] max_mono [2] spare [4..4+NBINS) hist [320..322) barriers
__global__ void k_init(uint32_t* ws) {
    int i = threadIdx.x;
    if (i == 0) ws[0] = 0xFFFFFFFFu;
    if (i == 1) ws[1] = 0u;
    if (i == 2) ws[2] = 0u;
    if (i >= 4 && i < 4 + NBINS) ws[i] = 0u;
    if (i >= BAR0 && i < BAR0 + 4) ws[i] = 0u;
}

__global__ void __launch_bounds__(TPB, 4) k_fused(const float* __restrict__ in,
                                                  float* __restrict__ out,
                                                  int n, uint32_t* ws) {
    __shared__ uint32_t h[NBINS * NCOPY];  // 32 KiB, reused per phase
    float* sf = (float*)h;

    const int gtid = blockIdx.x * blockDim.x + threadIdx.x;
    const int gstride = gridDim.x * blockDim.x;
    const int wave = threadIdx.x >> 6, lane = threadIdx.x & 63;
    const int n4 = n >> 2;
    const float4* in4 = (const float4*)in;
    const uint32_t expect = gridDim.x;

    // ===== Phase A: global min/max (MLP=8) =====
    {
        float vmin = INFINITY, vmax = -INFINITY;
        int i = gtid;
        for (; i + 7 * gstride < n4; i += 8 * gstride) {
            float4 v0 = in4[i];
            float4 v1 = in4[i + gstride];
            float4 v2 = in4[i + 2 * gstride];
            float4 v3 = in4[i + 3 * gstride];
            float4 v4 = in4[i + 4 * gstride];
            float4 v5 = in4[i + 5 * gstride];
            float4 v6 = in4[i + 6 * gstride];
            float4 v7 = in4[i + 7 * gstride];
            float mn0 = fminf(fminf(min4(v0), min4(v1)), fminf(min4(v2), min4(v3)));
            float mn1 = fminf(fminf(min4(v4), min4(v5)), fminf(min4(v6), min4(v7)));
            float mx0 = fmaxf(fmaxf(max4(v0), max4(v1)), fmaxf(max4(v2), max4(v3)));
            float mx1 = fmaxf(fmaxf(max4(v4), max4(v5)), fmaxf(max4(v6), max4(v7)));
            vmin = fminf(vmin, fminf(mn0, mn1));
            vmax = fmaxf(vmax, fmaxf(mx0, mx1));
        }
        for (; i < n4; i += gstride) {
            float4 v = in4[i];
            vmin = fminf(vmin, min4(v));
            vmax = fmaxf(vmax, max4(v));
        }
        for (int j = (n4 << 2) + gtid; j < n; j += gstride) {
            float v = in[j];
            vmin = fminf(vmin, v);
            vmax = fmaxf(vmax, v);
        }
#pragma unroll
        for (int off = 32; off > 0; off >>= 1) {
            vmin = fminf(vmin, __shfl_down(vmin, off));
            vmax = fmaxf(vmax, __shfl_down(vmax, off));
        }
        if (lane == 0) { sf[wave] = vmin; sf[8 + wave] = vmax; }
        __syncthreads();
        if (threadIdx.x == 0) {
            float m = sf[0], M = sf[8];
            for (int w = 1; w < 4; ++w) { m = fminf(m, sf[w]); M = fmaxf(M, sf[8 + w]); }
            atomicMin(&ws[0], f2mono(m));
            atomicMax(&ws[1], f2mono(M));
        }
    }
    grid_barrier(&ws[BAR0 + 0], expect);

    // ===== Phase B: histogram (per-bank sub-histograms, MLP=4) =====
    {
        float minv = mono2f(aload(&ws[0]));
        float maxv = mono2f(aload(&ws[1]));
        float invd = __fdiv_rn(256.0f, __fsub_rn(maxv, minv));
        int c = threadIdx.x & (NCOPY - 1);
        for (int i = threadIdx.x; i < NBINS * NCOPY; i += blockDim.x) h[i] = 0;
        __syncthreads();

        int i = gtid;
        for (; i + 3 * gstride < n4; i += 4 * gstride) {
            float4 q0 = in4[i];
            float4 q1 = in4[i + gstride];
            float4 q2 = in4[i + 2 * gstride];
            float4 q3 = in4[i + 3 * gstride];
            atomicAdd(&h[bin_of(q0.x, minv, invd) * NCOPY + c], 1u);
            atomicAdd(&h[bin_of(q0.y, minv, invd) * NCOPY + c], 1u);
            atomicAdd(&h[bin_of(q0.z, minv, invd) * NCOPY + c], 1u);
            atomicAdd(&h[bin_of(q0.w, minv, invd) * NCOPY + c], 1u);
            atomicAdd(&h[bin_of(q1.x, minv, invd) * NCOPY + c], 1u);
            atomicAdd(&h[bin_of(q1.y, minv, invd) * NCOPY + c], 1u);
            atomicAdd(&h[bin_of(q1.z, minv, invd) * NCOPY + c], 1u);
            atomicAdd(&h[bin_of(q1.w, minv, invd) * NCOPY + c], 1u);
            atomicAdd(&h[bin_of(q2.x, minv, invd) * NCOPY + c], 1u);
            atomicAdd(&h[bin_of(q2.y, minv, invd) * NCOPY + c], 1u);
            atomicAdd(&h[bin_of(q2.z, minv, invd) * NCOPY + c], 1u);
            atomicAdd(&h[bin_of(q2.w, minv, invd) * NCOPY + c], 1u);
            atomicAdd(&h[bin_of(q3.x, minv, invd) * NCOPY + c], 1u);
            atomicAdd(&h[bin_of(q3.y, minv, invd) * NCOPY + c], 1u);
            atomicAdd(&h[bin_of(q3.z, minv, invd) * NCOPY + c], 1u);
            atomicAdd(&h[bin_of(q3.w, minv, invd) * NCOPY + c], 1u);
        }
        for (; i < n4; i += gstride) {
            float4 q = in4[i];
            atomicAdd(&h[bin_of(q.x, minv, invd) * NCOPY + c], 1u);
            atomicAdd(&h[bin_of(q.y, minv, invd) * NCOPY + c], 1u);
            atomicAdd(&h[bin_of(q.z, minv, invd) * NCOPY + c], 1u);
            atomicAdd(&h[bin_of(q.w, minv, invd) * NCOPY + c], 1u);
        }
        for (int j = (n4 << 2) + gtid; j < n; j += gstride) {
            atomicAdd(&h[bin_of(in[j], minv, invd) * NCOPY + c], 1u);
        }
        __syncthreads();
        for (int b = threadIdx.x; b < NBINS; b += blockDim.x) {
            uint32_t s = 0;
#pragma unroll
            for (int k = 0; k < NCOPY; ++k) s += h[b * NCOPY + k];
            if (s) atomicAdd(&ws[4 + b], s);
        }
    }
    grid_barrier(&ws[BAR0 + 1], expect);

    // ===== Phase C: Otsu — EVERY block computes it redundantly (identical f32
    // math -> identical bit-exact threshold; removes the third grid barrier) =====
    float thresh;
    {
        float* cnt = sf;
        float* ctr = sf + NBINS;
        float* w1 = sf + 2 * NBINS;
        float* w2 = sf + 3 * NBINS;
        float* cs = sf + 4 * NBINS;
        float* csr = sf + 5 * NBINS;
        float* scan = sf + 6 * NBINS;
        float* tsh = sf + 7 * NBINS;
        int i = threadIdx.x;
        float minv = mono2f(aload(&ws[0]));
        float maxv = mono2f(aload(&ws[1]));
        float delta = __fdiv_rn(__fsub_rn(maxv, minv), 256.0f);

        cnt[i] = (float)aload(&ws[4 + i]);
        float e0 = edge_at(i, minv, delta);
        float e1 = edge_at(i + 1, minv, delta);
        ctr[i] = __fmul_rn(0.5f, __fadd_rn(e0, e1));
        __syncthreads();

        scan[i] = cnt[i]; __syncthreads();
        for (int off = 1; off < NBINS; off <<= 1) {
            float v = scan[i];
            if (i >= off) v = __fadd_rn(scan[i - off], v);
            __syncthreads(); scan[i] = v; __syncthreads();
        }
        w1[i] = scan[i]; __syncthreads();

        scan[i] = __fmul_rn(cnt[i], ctr[i]); __syncthreads();
        for (int off = 1; off < NBINS; off <<= 1) {
            float v = scan[i];
            if (i >= off) v = __fadd_rn(scan[i - off], v);
            __syncthreads(); scan[i] = v; __syncthreads();
        }
        cs[i] = scan[i]; __syncthreads();

        scan[i] = cnt[i]; __syncthreads();
        for (int off = 1; off < NBINS; off <<= 1) {
            float v = scan[i];
            if (i + off < NBINS) v = __fadd_rn(v, scan[i + off]);
            __syncthreads(); scan[i] = v; __syncthreads();
        }
        w2[i] = scan[i]; __syncthreads();

        scan[i] = __fmul_rn(cnt[i], ctr[i]); __syncthreads();
        for (int off = 1; off < NBINS; off <<= 1) {
            float v = scan[i];
            if (i + off < NBINS) v = __fadd_rn(v, scan[i + off]);
            __syncthreads(); scan[i] = v; __syncthreads();
        }
        csr[i] = scan[i]; __syncthreads();

        if (i < NBINS - 1) {
            float m1 = __fdiv_rn(cs[i], fmaxf(w1[i], 1.0f));
            float m2 = __fdiv_rn(csr[i + 1], fmaxf(w2[i + 1], 1.0f));
            float d = __fsub_rn(m1, m2);
            float sq = __fmul_rn(d, d);
            scan[i] = __fmul_rn(__fmul_rn(w1[i], w2[i + 1]), sq);
        }
        __syncthreads();
        if (i == 0) {
            int best = 0; float bv = scan[0];
            for (int k = 1; k < NBINS - 1; ++k) {
                float v = scan[k];
                if (v > bv) { bv = v; best = k; }  // first-max like jnp.argmax
            }
            tsh[0] = ctr[best];
        }
        __syncthreads();
        thresh = tsh[0];
        __syncthreads();  // everyone read tsh before any later LDS reuse
    }

    // ===== Phase D: binarize (MLP=4, plain stores) =====
    {
        float t = thresh;
        float4* out4 = (float4*)out;
        int i = gtid;
        for (; i + 3 * gstride < n4; i += 4 * gstride) {
            float4 v0 = in4[i];
            float4 v1 = in4[i + gstride];
            float4 v2 = in4[i + 2 * gstride];
            float4 v3 = in4[i + 3 * gstride];
            float4 r0, r1, r2, r3;
            r0.x = v0.x > t ? 1.0f : 0.0f; r0.y = v0.y > t ? 1.0f : 0.0f;
            r0.z = v0.z > t ? 1.0f : 0.0f; r0.w = v0.w > t ? 1.0f : 0.0f;
            r1.x = v1.x > t ? 1.0f : 0.0f; r1.y = v1.y > t ? 1.0f : 0.0f;
            r1.z = v1.z > t ? 1.0f : 0.0f; r1.w = v1.w > t ? 1.0f : 0.0f;
            r2.x = v2.x > t ? 1.0f : 0.0f; r2.y = v2.y > t ? 1.0f : 0.0f;
            r2.z = v2.z > t ? 1.0f : 0.0f; r2.w = v2.w > t ? 1.0f : 0.0f;
            r3.x = v3.x > t ? 1.0f : 0.0f; r3.y = v3.y > t ? 1.0f : 0.0f;
            r3.z = v3.z > t ? 1.0f : 0.0f; r3.w = v3.w > t ? 1.0f : 0.0f;
            out4[i] = r0;
            out4[i + gstride] = r1;
            out4[i + 2 * gstride] = r2;
            out4[i + 3 * gstride] = r3;
        }
        for (; i < n4; i += gstride) {
            float4 v = in4[i];
            float4 r;
            r.x = v.x > t ? 1.0f : 0.0f;
            r.y = v.y > t ? 1.0f : 0.0f;
            r.z = v.z > t ? 1.0f : 0.0f;
            r.w = v.w > t ? 1.0f : 0.0f;
            out4[i] = r;
        }
        for (int j = (n4 << 2) + gtid; j < n; j += gstride) {
            out[j] = in[j] > t ? 1.0f : 0.0f;
        }
    }
}

extern "C" void kernel_launch(void* const* d_in, const int* in_sizes, int n_in,
                              void* d_out, int out_size, void* d_ws, size_t ws_size,
                              hipStream_t stream) {
    const float* in = (const float*)d_in[0];
    float* out = (float*)d_out;
    uint32_t* ws = (uint32_t*)d_ws;
    int n = in_sizes[0];

    hipLaunchKernelGGL(k_init, dim3(1), dim3(512), 0, stream, ws);
    hipLaunchKernelGGL(k_fused, dim3(GRID_BLKS), dim3(TPB), 0, stream,
                       in, out, n, ws);
}

// Round 9
// 169.405 us; speedup vs baseline: 2.7080x; 1.9406x over previous
//
#include <hip/hip_runtime.h>
#include <stdint.h>

#define NBINS 256
#define NCOPY 32  // one sub-histogram per LDS bank; 32 KiB LDS -> 5 blocks/CU

// Monotonic float<->uint mapping so atomicMin/Max on uint32 order like floats.
__device__ __forceinline__ uint32_t f2mono(float f) {
    uint32_t u = __float_as_uint(f);
    return (u & 0x80000000u) ? ~u : (u | 0x80000000u);
}
__device__ __forceinline__ float mono2f(uint32_t u) {
    uint32_t b = (u & 0x80000000u) ? (u & 0x7FFFFFFFu) : ~u;
    return __uint_as_float(b);
}

// Exact replication of jnp.histogram edge: edges[i] = f32(f32(i*delta) + min)
// Separate roundings, NO fma contraction -> use _rn intrinsics.
__device__ __forceinline__ float edge_at(int i, float minv, float delta) {
    return __fadd_rn(__fmul_rn((float)i, delta), minv);
}

// ws layout (uint32 words):
// [0] min_mono  [1] max_mono  [2] spare  [4..4+NBINS) hist
__global__ void k_init(uint32_t* ws) {
    int i = threadIdx.x;
    if (i == 0) ws[0] = 0xFFFFFFFFu;
    if (i == 1) ws[1] = 0u;
    if (i == 2) ws[2] = 0u;
    if (i >= 4 && i < 4 + NBINS) ws[i] = 0u;
}

__device__ __forceinline__ float min4(float4 v) {
    return fminf(fminf(v.x, v.y), fminf(v.z, v.w));
}
__device__ __forceinline__ float max4(float4 v) {
    return fmaxf(fmaxf(v.x, v.y), fmaxf(v.z, v.w));
}

__global__ void __launch_bounds__(256, 4) k_minmax(const float* __restrict__ in,
                                                   int n, uint32_t* ws) {
    int tid = blockIdx.x * blockDim.x + threadIdx.x;
    int stride = gridDim.x * blockDim.x;
    int n4 = n >> 2;
    const float4* in4 = (const float4*)in;
    float vmin = INFINITY, vmax = -INFINITY;

    // MLP=16: sixteen independent float4 loads in flight (~80 VGPR, 16 waves/CU).
    int i = tid;
    for (; i + 15 * stride < n4; i += 16 * stride) {
        float4 v[16];
#pragma unroll
        for (int k = 0; k < 16; ++k) v[k] = in4[i + k * stride];
        float mn = min4(v[0]), mx = max4(v[0]);
#pragma unroll
        for (int k = 1; k < 16; ++k) {
            mn = fminf(mn, min4(v[k]));
            mx = fmaxf(mx, max4(v[k]));
        }
        vmin = fminf(vmin, mn);
        vmax = fmaxf(vmax, mx);
    }
    for (; i < n4; i += stride) {
        float4 v = in4[i];
        vmin = fminf(vmin, min4(v));
        vmax = fmaxf(vmax, max4(v));
    }
    for (int j = (n4 << 2) + tid; j < n; j += stride) {
        float v = in[j];
        vmin = fminf(vmin, v);
        vmax = fmaxf(vmax, v);
    }
#pragma unroll
    for (int off = 32; off > 0; off >>= 1) {
        vmin = fminf(vmin, __shfl_down(vmin, off));
        vmax = fmaxf(vmax, __shfl_down(vmax, off));
    }
    __shared__ float smin[4], smax[4];  // 256 threads = 4 waves
    int wave = threadIdx.x >> 6, lane = threadIdx.x & 63;
    if (lane == 0) { smin[wave] = vmin; smax[wave] = vmax; }
    __syncthreads();
    if (threadIdx.x == 0) {
        float m = smin[0], M = smax[0];
        for (int w = 1; w < 4; ++w) { m = fminf(m, smin[w]); M = fmaxf(M, smax[w]); }
        atomicMin(&ws[0], f2mono(m));
        atomicMax(&ws[1], f2mono(M));
    }
}

// bin = clamp((v-min)*256/(max-min), 0, 255). ±1ulp edge misbinning shifts a
// handful of counts out of 33.5M -> var12 argmax unaffected; threshold value
// itself stays bit-exact (computed from min/max only). v==max subsumed by clamp.
__device__ __forceinline__ int bin_of(float v, float minv, float invd) {
    float t = (v - minv) * invd;
    t = fminf(fmaxf(t, 0.0f), 255.0f);
    return (int)t;
}

__global__ void __launch_bounds__(256) k_hist(const float* __restrict__ in,
                                              int n, uint32_t* ws) {
    // h[bin*32 + (lane&31)]: bank = lane&31 -> a wave's ds_add is a free
    // 2-way bank alias; same-address only when lane l and l+32 share a bin.
    __shared__ uint32_t h[NBINS * NCOPY];
    for (int i = threadIdx.x; i < NBINS * NCOPY; i += blockDim.x) h[i] = 0;
    __syncthreads();
    float minv = mono2f(ws[0]);
    float maxv = mono2f(ws[1]);
    float invd = __fdiv_rn(256.0f, __fsub_rn(maxv, minv));
    int c = threadIdx.x & (NCOPY - 1);

    int tid = blockIdx.x * blockDim.x + threadIdx.x;
    int stride = gridDim.x * blockDim.x;
    int n4 = n >> 2;
    const float4* in4 = (const float4*)in;
    int i = tid;
    for (; i + 3 * stride < n4; i += 4 * stride) {
        float4 q0 = in4[i];
        float4 q1 = in4[i + stride];
        float4 q2 = in4[i + 2 * stride];
        float4 q3 = in4[i + 3 * stride];
        atomicAdd(&h[bin_of(q0.x, minv, invd) * NCOPY + c], 1u);
        atomicAdd(&h[bin_of(q0.y, minv, invd) * NCOPY + c], 1u);
        atomicAdd(&h[bin_of(q0.z, minv, invd) * NCOPY + c], 1u);
        atomicAdd(&h[bin_of(q0.w, minv, invd) * NCOPY + c], 1u);
        atomicAdd(&h[bin_of(q1.x, minv, invd) * NCOPY + c], 1u);
        atomicAdd(&h[bin_of(q1.y, minv, invd) * NCOPY + c], 1u);
        atomicAdd(&h[bin_of(q1.z, minv, invd) * NCOPY + c], 1u);
        atomicAdd(&h[bin_of(q1.w, minv, invd) * NCOPY + c], 1u);
        atomicAdd(&h[bin_of(q2.x, minv, invd) * NCOPY + c], 1u);
        atomicAdd(&h[bin_of(q2.y, minv, invd) * NCOPY + c], 1u);
        atomicAdd(&h[bin_of(q2.z, minv, invd) * NCOPY + c], 1u);
        atomicAdd(&h[bin_of(q2.w, minv, invd) * NCOPY + c], 1u);
        atomicAdd(&h[bin_of(q3.x, minv, invd) * NCOPY + c], 1u);
        atomicAdd(&h[bin_of(q3.y, minv, invd) * NCOPY + c], 1u);
        atomicAdd(&h[bin_of(q3.z, minv, invd) * NCOPY + c], 1u);
        atomicAdd(&h[bin_of(q3.w, minv, invd) * NCOPY + c], 1u);
    }
    for (; i < n4; i += stride) {
        float4 q = in4[i];
        atomicAdd(&h[bin_of(q.x, minv, invd) * NCOPY + c], 1u);
        atomicAdd(&h[bin_of(q.y, minv, invd) * NCOPY + c], 1u);
        atomicAdd(&h[bin_of(q.z, minv, invd) * NCOPY + c], 1u);
        atomicAdd(&h[bin_of(q.w, minv, invd) * NCOPY + c], 1u);
    }
    for (int j = (n4 << 2) + tid; j < n; j += stride) {
        atomicAdd(&h[bin_of(in[j], minv, invd) * NCOPY + c], 1u);
    }
    __syncthreads();
    for (int b = threadIdx.x; b < NBINS; b += blockDim.x) {
        uint32_t s = 0;
#pragma unroll
        for (int k = 0; k < NCOPY; ++k) s += h[b * NCOPY + k];
        if (s) atomicAdd(&ws[4 + b], s);
    }
}

// Binarize with Otsu folded in: EVERY block redundantly computes the threshold
// from the global histogram (identical f32 math -> identical bit-exact result),
// then streams its slice. Removes the separate otsu dispatch + launch gap.
__global__ void __launch_bounds__(256) k_bin(const float* __restrict__ in,
                                             float* __restrict__ out,
                                             int n, const uint32_t* __restrict__ ws) {
    __shared__ float cnt[NBINS], ctr[NBINS], w1[NBINS], w2[NBINS],
                     cs[NBINS], csr[NBINS], scan[NBINS], tsh[1];
    {
        int i = threadIdx.x;
        float minv = mono2f(ws[0]);
        float maxv = mono2f(ws[1]);
        float delta = __fdiv_rn(__fsub_rn(maxv, minv), 256.0f);

        cnt[i] = (float)ws[4 + i];
        float e0 = edge_at(i, minv, delta);
        float e1 = edge_at(i + 1, minv, delta);
        ctr[i] = __fmul_rn(0.5f, __fadd_rn(e0, e1));
        __syncthreads();

        // inclusive prefix scan of cnt -> w1
        scan[i] = cnt[i]; __syncthreads();
        for (int off = 1; off < NBINS; off <<= 1) {
            float v = scan[i];
            if (i >= off) v = __fadd_rn(scan[i - off], v);
            __syncthreads(); scan[i] = v; __syncthreads();
        }
        w1[i] = scan[i]; __syncthreads();

        // inclusive prefix scan of cnt*ctr -> cs
        scan[i] = __fmul_rn(cnt[i], ctr[i]); __syncthreads();
        for (int off = 1; off < NBINS; off <<= 1) {
            float v = scan[i];
            if (i >= off) v = __fadd_rn(scan[i - off], v);
            __syncthreads(); scan[i] = v; __syncthreads();
        }
        cs[i] = scan[i]; __syncthreads();

        // inclusive suffix scan of cnt -> w2
        scan[i] = cnt[i]; __syncthreads();
        for (int off = 1; off < NBINS; off <<= 1) {
            float v = scan[i];
            if (i + off < NBINS) v = __fadd_rn(v, scan[i + off]);
            __syncthreads(); scan[i] = v; __syncthreads();
        }
        w2[i] = scan[i]; __syncthreads();

        // inclusive suffix scan of cnt*ctr -> csr
        scan[i] = __fmul_rn(cnt[i], ctr[i]); __syncthreads();
        for (int off = 1; off < NBINS; off <<= 1) {
            float v = scan[i];
            if (i + off < NBINS) v = __fadd_rn(v, scan[i + off]);
            __syncthreads(); scan[i] = v; __syncthreads();
        }
        csr[i] = scan[i]; __syncthreads();

        // var12[i] = (w1[i]*w2[i+1]) * (m1[i]-m2[i+1])^2, i in [0, 254]
        if (i < NBINS - 1) {
            float m1 = __fdiv_rn(cs[i], fmaxf(w1[i], 1.0f));
            float m2 = __fdiv_rn(csr[i + 1], fmaxf(w2[i + 1], 1.0f));
            float d = __fsub_rn(m1, m2);
            float sq = __fmul_rn(d, d);
            scan[i] = __fmul_rn(__fmul_rn(w1[i], w2[i + 1]), sq);
        }
        __syncthreads();
        if (i == 0) {
            int best = 0; float bv = scan[0];
            for (int k = 1; k < NBINS - 1; ++k) {
                float v = scan[k];
                if (v > bv) { bv = v; best = k; }  // first-max like jnp.argmax
            }
            tsh[0] = ctr[best];
        }
        __syncthreads();
    }
    float t = tsh[0];

    int tid = blockIdx.x * blockDim.x + threadIdx.x;
    int stride = gridDim.x * blockDim.x;
    int n4 = n >> 2;
    const float4* in4 = (const float4*)in;
    float4* out4 = (float4*)out;
    int i = tid;
    for (; i + 3 * stride < n4; i += 4 * stride) {
        float4 v0 = in4[i];
        float4 v1 = in4[i + stride];
        float4 v2 = in4[i + 2 * stride];
        float4 v3 = in4[i + 3 * stride];
        float4 r0, r1, r2, r3;
        r0.x = v0.x > t ? 1.0f : 0.0f; r0.y = v0.y > t ? 1.0f : 0.0f;
        r0.z = v0.z > t ? 1.0f : 0.0f; r0.w = v0.w > t ? 1.0f : 0.0f;
        r1.x = v1.x > t ? 1.0f : 0.0f; r1.y = v1.y > t ? 1.0f : 0.0f;
        r1.z = v1.z > t ? 1.0f : 0.0f; r1.w = v1.w > t ? 1.0f : 0.0f;
        r2.x = v2.x > t ? 1.0f : 0.0f; r2.y = v2.y > t ? 1.0f : 0.0f;
        r2.z = v2.z > t ? 1.0f : 0.0f; r2.w = v2.w > t ? 1.0f : 0.0f;
        r3.x = v3.x > t ? 1.0f : 0.0f; r3.y = v3.y > t ? 1.0f : 0.0f;
        r3.z = v3.z > t ? 1.0f : 0.0f; r3.w = v3.w > t ? 1.0f : 0.0f;
        out4[i] = r0;
        out4[i + stride] = r1;
        out4[i + 2 * stride] = r2;
        out4[i + 3 * stride] = r3;
    }
    for (; i < n4; i += stride) {
        float4 v = in4[i];
        float4 r;
        r.x = v.x > t ? 1.0f : 0.0f;
        r.y = v.y > t ? 1.0f : 0.0f;
        r.z = v.z > t ? 1.0f : 0.0f;
        r.w = v.w > t ? 1.0f : 0.0f;
        out4[i] = r;
    }
    for (int j = (n4 << 2) + tid; j < n; j += stride) {
        out[j] = in[j] > t ? 1.0f : 0.0f;
    }
}

extern "C" void kernel_launch(void* const* d_in, const int* in_sizes, int n_in,
                              void* d_out, int out_size, void* d_ws, size_t ws_size,
                              hipStream_t stream) {
    const float* in = (const float*)d_in[0];
    float* out = (float*)d_out;
    uint32_t* ws = (uint32_t*)d_ws;
    int n = in_sizes[0];

    const int threads = 256;
    const int blocks = 2048;       // 256 CU * 8, grid-stride
    const int hist_blocks = 1280;  // 5 blocks/CU resident (32 KiB LDS each)

    hipLaunchKernelGGL(k_init, dim3(1), dim3(512), 0, stream, ws);
    hipLaunchKernelGGL(k_minmax, dim3(blocks), dim3(threads), 0, stream, in, n, ws);
    hipLaunchKernelGGL(k_hist, dim3(hist_blocks), dim3(threads), 0, stream, in, n, ws);
    hipLaunchKernelGGL(k_bin, dim3(blocks), dim3(threads), 0, stream, in, out, n, ws);
}